// Round 1
// baseline (401.420 us; speedup 1.0000x reference)
//
#include <hip/hip_runtime.h>
#include <stdint.h>

#define NBATCH 16384
#define TT     20
#define CC     256
#define NB     2
#define RPAD   48
#define LDK    264   // LDS row stride in bf16 elems (256 + 8 pad -> breaks bank conflicts)

typedef __bf16 bf16x8 __attribute__((ext_vector_type(8)));
typedef float  f32x4  __attribute__((ext_vector_type(4)));

// Active-column tables derived from tb_mask(T=20, win=3):
// t=0,1:{0,1,2}  t=2:{0,1,2,3}  t=3..15:{t,t+1}  t=16: uniform 1/20  t=17..19:{17,18,19}
__constant__ int8_t c_CNT[TT]     = {3,3,4,2,2,2,2,2,2,2,2,2,2,2,2,2,0,3,3,3};
__constant__ int8_t c_OFF[TT]     = {0,3,6,10,12,14,16,18,20,22,24,26,28,30,32,34,0,36,39,42};
__constant__ int8_t c_COLS[TT][4] = {
    {0,1,2,0},{0,1,2,0},{0,1,2,3},
    {3,4,0,0},{4,5,0,0},{5,6,0,0},{6,7,0,0},{7,8,0,0},{8,9,0,0},
    {9,10,0,0},{10,11,0,0},{11,12,0,0},{12,13,0,0},{13,14,0,0},
    {14,15,0,0},{15,16,0,0},{0,0,0,0},
    {17,18,19,0},{17,18,19,0},{17,18,19,0}};
__constant__ int8_t c_PT[45] = {0,0,0,1,1,1,2,2,2,2,3,3,4,4,5,5,6,6,7,7,8,8,9,9,
                                10,10,11,11,12,12,13,13,14,14,15,15,17,17,17,18,18,18,19,19,19};
__constant__ int8_t c_PS[45] = {0,1,2,0,1,2,0,1,2,3,3,4,4,5,5,6,6,7,7,8,8,9,9,10,
                                10,11,11,12,12,13,13,14,14,15,15,16,17,18,19,17,18,19,17,18,19};

__device__ __forceinline__ uint32_t f2bf1(float f) {
    uint32_t u = __builtin_bit_cast(uint32_t, f);
    return (u + 0x7fffu + ((u >> 16) & 1u)) >> 16;   // RNE
}
__device__ __forceinline__ uint32_t pack2(float a, float b) { return f2bf1(a) | (f2bf1(b) << 16); }
__device__ __forceinline__ float bflo(uint32_t u) { return __builtin_bit_cast(float, u << 16); }
__device__ __forceinline__ float bfhi(uint32_t u) { return __builtin_bit_cast(float, u & 0xffff0000u); }

// Prep: mqkT[n][k] = sum_h Wk[h,n]*Wq[h,k] / 16  (B^T layout for MFMA B-frags),
//       wvb[n][k]  = bf16(Wv[n][k])              (already B^T layout).
__global__ void prep_kernel(const float* __restrict__ Wq, const float* __restrict__ Wk,
                            const float* __restrict__ Wv, uint16_t* __restrict__ mqkT,
                            uint16_t* __restrict__ wvb) {
    const int n = blockIdx.x;
    const int k = threadIdx.x;
    float acc = 0.f;
    for (int h = 0; h < CC; ++h)
        acc = fmaf(Wk[h * CC + n], Wq[h * CC + k], acc);
    mqkT[n * CC + k] = (uint16_t)f2bf1(acc * 0.0625f);
    wvb[n * CC + k]  = (uint16_t)f2bf1(Wv[n * CC + k]);
}

// 48x256 GEMM: A (bf16, LDS, stride LDK) x B^T (bf16, global, stride CC) -> acc[3][4] 16x16 tiles.
// A-frag: lane l holds A[l&15][8*(l>>4)+j]; B-frag: B[8*(l>>4)+j][l&15] = BT[l&15][8*(l>>4)+j].
__device__ __forceinline__ void gemm48(const uint16_t* __restrict__ sA,
                                       const uint16_t* __restrict__ Bg,
                                       int lrow, int lk8, f32x4 acc[3][4]) {
#pragma unroll
    for (int kk = 0; kk < 8; ++kk) {
        bf16x8 av[3], bv[4];
#pragma unroll
        for (int rt = 0; rt < 3; ++rt) {
            uint4 u = *(const uint4*)(sA + (rt * 16 + lrow) * LDK + kk * 32 + lk8);
            av[rt] = __builtin_bit_cast(bf16x8, u);
        }
#pragma unroll
        for (int ct = 0; ct < 4; ++ct) {
            uint4 u = *(const uint4*)(Bg + (ct * 16 + lrow) * CC + kk * 32 + lk8);
            bv[ct] = __builtin_bit_cast(bf16x8, u);
        }
#pragma unroll
        for (int rt = 0; rt < 3; ++rt)
#pragma unroll
            for (int ct = 0; ct < 4; ++ct)
                acc[rt][ct] = __builtin_amdgcn_mfma_f32_16x16x32_bf16(av[rt], bv[ct], acc[rt][ct], 0, 0, 0);
    }
}

// D layout (m89-verified): col = lane&15, row = 4*(lane>>4)+i.
__device__ __forceinline__ void store48(uint16_t* __restrict__ sD, int w, int lane, f32x4 acc[3][4]) {
    const int drow = (lane >> 4) << 2;
    const int dcol = lane & 15;
#pragma unroll
    for (int rt = 0; rt < 3; ++rt)
#pragma unroll
        for (int ct = 0; ct < 4; ++ct)
#pragma unroll
            for (int i = 0; i < 4; ++i)
                sD[(rt * 16 + drow + i) * LDK + (w * 64 + ct * 16 + dcol)] =
                    (uint16_t)f2bf1(acc[rt][ct][i]);
}

__device__ __forceinline__ void acc8(float* o, uint4 uv, float wgt) {
    o[0] = fmaf(bflo(uv.x), wgt, o[0]);
    o[1] = fmaf(bfhi(uv.x), wgt, o[1]);
    o[2] = fmaf(bflo(uv.y), wgt, o[2]);
    o[3] = fmaf(bfhi(uv.y), wgt, o[3]);
    o[4] = fmaf(bflo(uv.z), wgt, o[4]);
    o[5] = fmaf(bfhi(uv.z), wgt, o[5]);
    o[6] = fmaf(bflo(uv.w), wgt, o[6]);
    o[7] = fmaf(bfhi(uv.w), wgt, o[7]);
}

__global__ __launch_bounds__(256, 3)
void attn_main(const float* __restrict__ f1g, const float* __restrict__ f2g,
               const uint16_t* __restrict__ mqkT, const uint16_t* __restrict__ wvb,
               float* __restrict__ outg) {
    __shared__ uint16_t sA2[RPAD * LDK];   // feat2 (bf16), lives whole kernel
    __shared__ uint16_t sA1[RPAD * LDK];   // feat1 -> t1 -> v   (reused)
    __shared__ float s_sim[NB * 45];
    __shared__ float s_attn[NB * TT * 4];

    const int tid  = threadIdx.x;
    const int lane = tid & 63;
    const int w    = tid >> 6;
    const int lrow = lane & 15;
    const int lk8  = (lane >> 4) << 3;
    const int b0   = blockIdx.x * NB;

    const float* f1 = f1g + (size_t)b0 * TT * CC;
    const float* f2 = f2g + (size_t)b0 * TT * CC;

    // ---- stage feat1/feat2 -> LDS bf16 (40 rows x 256, coalesced float4) ----
#pragma unroll
    for (int i = 0; i < 10; ++i) {
        int idx = tid + (i << 8);          // 0..2559
        int r   = idx >> 6;                // 0..39
        int c4  = (idx & 63) << 2;         // 0..252
        float4 a = *(const float4*)(f1 + (idx << 2));
        float4 b = *(const float4*)(f2 + (idx << 2));
        uint2 ua; ua.x = pack2(a.x, a.y); ua.y = pack2(a.z, a.w);
        uint2 ub; ub.x = pack2(b.x, b.y); ub.y = pack2(b.z, b.w);
        *(uint2*)&sA1[r * LDK + c4] = ua;
        *(uint2*)&sA2[r * LDK + c4] = ub;
    }
    for (int i = tid; i < 8 * LDK; i += 256) {   // zero pad rows 40..47
        sA1[40 * LDK + i] = 0;
        sA2[40 * LDK + i] = 0;
    }
    __syncthreads();

    // ---- GEMM1: t1 = feat1 * Mqk ----
    f32x4 acc[3][4];
#pragma unroll
    for (int a = 0; a < 3; ++a)
#pragma unroll
        for (int b = 0; b < 4; ++b)
            acc[a][b] = f32x4{0.f, 0.f, 0.f, 0.f};
    gemm48(sA1, mqkT + w * 64 * CC, lrow, lk8, acc);
    __syncthreads();                 // all A1 reads done before overwrite
    store48(sA1, w, lane, acc);      // sA1 now holds t1 (bf16)
    __syncthreads();

    // ---- sparse sim: 90 dots, 2 lanes per dot ----
    if (tid < 180) {
        int d  = tid >> 1;
        int p  = tid & 1;
        int lb = (d >= 45) ? 1 : 0;
        int pd = d - lb * 45;
        int t = c_PT[pd], s = c_PS[pd];
        const uint16_t* ap = &sA1[(lb * 20 + t) * LDK + (p << 7)];
        const uint16_t* bp = &sA2[(lb * 20 + s) * LDK + (p << 7)];
        float da = 0.f;
#pragma unroll
        for (int c = 0; c < 128; c += 8) {
            uint4 ua = *(const uint4*)(ap + c);
            uint4 ub = *(const uint4*)(bp + c);
            da = fmaf(bflo(ua.x), bflo(ub.x), da);
            da = fmaf(bfhi(ua.x), bfhi(ub.x), da);
            da = fmaf(bflo(ua.y), bflo(ub.y), da);
            da = fmaf(bfhi(ua.y), bfhi(ub.y), da);
            da = fmaf(bflo(ua.z), bflo(ub.z), da);
            da = fmaf(bfhi(ua.z), bfhi(ub.z), da);
            da = fmaf(bflo(ua.w), bflo(ub.w), da);
            da = fmaf(bfhi(ua.w), bfhi(ub.w), da);
        }
        da += __shfl_xor(da, 1);
        if (p == 0) s_sim[d] = da;
    }
    __syncthreads();

    // ---- GEMM2: v = feat2 * Wv^T ----
#pragma unroll
    for (int a = 0; a < 3; ++a)
#pragma unroll
        for (int b = 0; b < 4; ++b)
            acc[a][b] = f32x4{0.f, 0.f, 0.f, 0.f};
    gemm48(sA2, wvb + w * 64 * CC, lrow, lk8, acc);

    // ---- sparse softmax (one thread per (batch,row)) ----
    if (tid < NB * TT) {
        int lb = (tid >= TT) ? 1 : 0;
        int t  = tid - lb * TT;
        int cnt = c_CNT[t];
        if (cnt) {
            int off = lb * 45 + c_OFF[t];
            float m = -1e30f;
#pragma unroll
            for (int j = 0; j < 4; ++j)
                if (j < cnt) m = fmaxf(m, s_sim[off + j]);
            float ee[4] = {0.f, 0.f, 0.f, 0.f};
            float ssum = 0.f;
#pragma unroll
            for (int j = 0; j < 4; ++j)
                if (j < cnt) { ee[j] = __expf(s_sim[off + j] - m); ssum += ee[j]; }
            float inv = 1.f / ssum;
#pragma unroll
            for (int j = 0; j < 4; ++j)
                if (j < cnt) s_attn[(lb * TT + t) * 4 + j] = ee[j] * inv;
        }
    }
    __syncthreads();                 // t1 reads (sim) done; attn visible
    store48(sA1, w, lane, acc);      // sA1 now holds v (bf16)
    __syncthreads();

    // ---- sparse combine: out[r] = sum_s attn[r,s] * v[s] ----
    const size_t outbase = (size_t)b0 * TT * CC;
#pragma unroll
    for (int i = 0; i < 5; ++i) {
        int u  = tid + (i << 8);       // 0..1279
        int r  = u >> 5;               // 0..39
        int ch = (u & 31) << 3;        // 0..248
        int lb = (r >= TT) ? 1 : 0;
        int t  = r - lb * TT;
        float o[8] = {0.f, 0.f, 0.f, 0.f, 0.f, 0.f, 0.f, 0.f};
        if (t == 16) {
            const uint16_t* base = &sA1[(lb * TT) * LDK + ch];
#pragma unroll
            for (int s = 0; s < TT; ++s) {
                uint4 uv = *(const uint4*)(base + s * LDK);
                acc8(o, uv, 0.05f);
            }
        } else {
            int cnt = c_CNT[t];
#pragma unroll
            for (int j = 0; j < 4; ++j) {
                if (j < cnt) {
                    float wgt = s_attn[(lb * TT + t) * 4 + j];
                    int s = c_COLS[t][j];
                    uint4 uv = *(const uint4*)&sA1[(lb * TT + s) * LDK + ch];
                    acc8(o, uv, wgt);
                }
            }
        }
        float* op = outg + outbase + (size_t)r * CC + ch;
        *(float4*)op       = make_float4(o[0], o[1], o[2], o[3]);
        *(float4*)(op + 4) = make_float4(o[4], o[5], o[6], o[7]);
    }
}

extern "C" void kernel_launch(void* const* d_in, const int* in_sizes, int n_in,
                              void* d_out, int out_size, void* d_ws, size_t ws_size,
                              hipStream_t stream) {
    const float* feat1 = (const float*)d_in[0];
    const float* feat2 = (const float*)d_in[1];
    const float* Wq    = (const float*)d_in[2];
    const float* Wk    = (const float*)d_in[3];
    const float* Wv    = (const float*)d_in[4];
    uint16_t* mqkT = (uint16_t*)d_ws;
    uint16_t* wvb  = mqkT + CC * CC;

    prep_kernel<<<CC, CC, 0, stream>>>(Wq, Wk, Wv, mqkT, wvb);
    attn_main<<<NBATCH / NB, 256, 0, stream>>>(feat1, feat2, mqkT, wvb, (float*)d_out);
}